// Round 7
// baseline (255.823 us; speedup 1.0000x reference)
//
#include <hip/hip_runtime.h>

// Involution via bf16 MFMA tap-GEMM, operand-swapped (D[t][px]).
// R7: LDS-free, barrier-free invol_main. x/hv/kwb are all L2-resident
// (~21MB total), so LDS staging paid barrier + occupancy costs to cache
// already-cached data. Now: hb frags straight from global hv; involution
// x reads straight from L2 with clamped addresses (geometry precomputed,
// iter-invariant). Occupancy becomes VGPR-limited, no syncthreads at all.

#define C_    256
#define HID_  64
#define KS_   7
#define KK_   49
#define G_    256
#define H_    64
#define W_    64
#define HW_   4096
#define BN_EPS 1e-5f

typedef __attribute__((ext_vector_type(8))) short bf16x8;
typedef __attribute__((ext_vector_type(4))) float f32x4;

__device__ __forceinline__ ushort f2bf(float f) {
    unsigned u = __float_as_uint(f);
    return (ushort)((u + 0x7fffu + ((u >> 16) & 1u)) >> 16);   // RNE
}
__device__ __forceinline__ float bf2f(ushort s) {
    return __uint_as_float((unsigned)s << 16);
}

// ---------------------------------------------------------------- prep ----
// blocks 0..255:  kwb[g][t][k] bf16 (t<49 data, 51..63 zero; skip t=49,50)
// block 256:      rwT[k][o] = reduce_w[o][k]*bn_inv[o]; betp[o]
// block 257:      kbp[g][t] = bias (t<49), 0 (t in 50..63); t=49 owned below
// blocks 258+g:   kwb[g][49/50][k] = colsum(kw) hi/lo; kbp[g][49] = sum(kb)
__global__ __launch_bounds__(256) void prep_kernel(
    const float* __restrict__ kw, const float* __restrict__ kb,
    const float* __restrict__ reduce_w,
    const float* __restrict__ bn_gamma, const float* __restrict__ bn_beta,
    const float* __restrict__ bn_mean, const float* __restrict__ bn_var,
    ushort* __restrict__ kwb, float* __restrict__ rwT, float* __restrict__ betp,
    float* __restrict__ kbp)
{
    const int bid = blockIdx.x;
    if (bid < 256) {
        int idx  = bid * 256 + threadIdx.x;
        int base = idx * 16;
        int g    = base >> 12;
        int rem  = base & 4095;
        int t    = rem >> 6;
        int k0   = rem & 63;
        if (t == 49 || t == 50) return;      // owned by u-row blocks
        union { ushort s[16]; uint4 v[2]; } u;
        if (t < KK_) {
            const float* src = kw + ((size_t)(g * KK_ + t)) * HID_ + k0;
            #pragma unroll
            for (int i = 0; i < 16; ++i) u.s[i] = f2bf(src[i]);
        } else {
            #pragma unroll
            for (int i = 0; i < 16; ++i) u.s[i] = 0;
        }
        uint4* dst = (uint4*)(kwb + base);
        dst[0] = u.v[0];
        dst[1] = u.v[1];
    } else if (bid == 256) {
        int k = threadIdx.x;
        #pragma unroll 1
        for (int o = 0; o < HID_; ++o) {
            float inv = bn_gamma[o] * rsqrtf(bn_var[o] + BN_EPS);
            rwT[k * HID_ + o] = reduce_w[o * C_ + k] * inv;
        }
        if (k < HID_) {
            float inv = bn_gamma[k] * rsqrtf(bn_var[k] + BN_EPS);
            betp[k] = bn_beta[k] - bn_mean[k] * inv;
        }
    } else if (bid == 257) {
        for (int i = threadIdx.x; i < G_ * 64; i += 256) {
            int g = i >> 6, t = i & 63;
            if (t == 49) continue;           // written by u-row block
            kbp[i] = (t < KK_) ? kb[g * KK_ + t] : 0.f;
        }
    } else {
        const int g = bid - 258;
        __shared__ float part[4][64];
        const int k  = threadIdx.x & 63;
        const int pr = threadIdx.x >> 6;
        const int t0 = pr * 13;
        const int t1 = (t0 + 13 < KK_) ? t0 + 13 : KK_;
        float s = 0.f;
        for (int t = t0; t < t1; ++t)
            s += kw[((size_t)(g * KK_ + t)) * HID_ + k];
        part[pr][k] = s;
        __syncthreads();
        if (threadIdx.x < 64) {
            float u = part[0][k] + part[1][k] + part[2][k] + part[3][k];
            ushort uh = f2bf(u);
            ushort ul = f2bf(u - bf2f(uh));
            kwb[(size_t)g * 4096 + 49 * 64 + k] = uh;
            kwb[(size_t)g * 4096 + 50 * 64 + k] = ul;
            // bias-sum: wave-parallel reduce over the 49 taps
            float bs = (k < KK_) ? kb[g * KK_ + k] : 0.f;
            #pragma unroll
            for (int off = 32; off >= 1; off >>= 1) bs += __shfl_xor(bs, off);
            if (k == 0) kbp[g * 64 + 49] = bs;
        }
    }
}

// ----------------------------------------------------------------- hv1 ----
__global__ __launch_bounds__(256) void hv1_kernel(
    const float* __restrict__ x, const float* __restrict__ rwT,
    float* __restrict__ hvp, int npx)
{
    const int lane = threadIdx.x & 63;
    const int wq   = __builtin_amdgcn_readfirstlane(threadIdx.x >> 6);
    const int kq   = blockIdx.y;
    const int p    = blockIdx.x * 64 + lane;
    const int b    = p >> 12;
    const int hw   = p & 4095;

    float acc[16];
    #pragma unroll
    for (int j = 0; j < 16; ++j) acc[j] = 0.f;

    const float* xp = x + ((size_t)b * C_ + kq * 64) * HW_ + hw;
    const float* rw = rwT + (kq * 64) * HID_ + wq * 16;
    #pragma unroll 8
    for (int kk = 0; kk < 64; ++kk) {
        float xk = xp[(size_t)kk * HW_];
        #pragma unroll
        for (int j = 0; j < 16; ++j) acc[j] = fmaf(xk, rw[kk * HID_ + j], acc[j]);
    }
    float* dst = hvp + ((size_t)(kq * 64 + wq * 16)) * npx + p;
    #pragma unroll
    for (int j = 0; j < 16; ++j) dst[(size_t)j * npx] = acc[j];
}

// ----------------------------------------------------------------- hv2 ----
__global__ __launch_bounds__(256) void hv2_kernel(
    const float* __restrict__ hvp, const float* __restrict__ betp,
    ushort* __restrict__ hv, int npx)
{
    const int p  = blockIdx.x * 256 + threadIdx.x;
    const int o0 = blockIdx.y * 4;
    ushort s[4];
    #pragma unroll
    for (int j = 0; j < 4; ++j) {
        float v = 0.f;
        #pragma unroll
        for (int kq = 0; kq < 4; ++kq)
            v += hvp[(size_t)(kq * 64 + o0 + j) * npx + p];
        s[j] = f2bf(fmaxf(v + betp[o0 + j], 0.f));
    }
    uint2 w;
    w.x = (uint)s[0] | ((uint)s[1] << 16);
    w.y = (uint)s[2] | ((uint)s[3] << 16);
    *(uint2*)(hv + (size_t)p * HID_ + o0) = w;
}

// ---------------------------------------------------------------- main ----
// LDS-free: hb from global hv, x from global (L2). No barriers.
__global__ __launch_bounds__(256) void invol_main(
    const float* __restrict__ x, const ushort* __restrict__ hv,
    const ushort* __restrict__ kwb, const float* __restrict__ kbp,
    float* __restrict__ out)
{
    const int tid  = threadIdx.x;
    const int lane = tid & 63;
    const int wave = __builtin_amdgcn_readfirstlane(tid >> 6);
    const int b  = blockIdx.x >> 6;
    const int y  = blockIdx.x & 63;
    const int gy = blockIdx.y;
    const int rowpix = (b << 12) + (y << 6);
    const int l15 = lane & 15;
    const int l4  = lane >> 4;

    // B frags (hv) straight from global: row px = pn*16+l15 of this image row
    bf16x8 hb[2][4];
    #pragma unroll
    for (int ks = 0; ks < 2; ++ks)
        #pragma unroll
        for (int pn = 0; pn < 4; ++pn) {
            const char* p = (const char*)(hv + (size_t)(rowpix + pn * 16 + l15) * HID_)
                            + ks * 64 + l4 * 16;
            hb[ks][pn] = *(const bf16x8*)p;
        }

    // per-lane tap geometry (iter-invariant): t = tm*16 + l4*4 + r  (t<48)
    int row64[3][4];    // clamped row * 64
    int jm3[3][4];      // j - 3
    unsigned rokb = 0;  // row-valid bits (bit tm*4+r)
    #pragma unroll
    for (int tm = 0; tm < 3; ++tm)
        #pragma unroll
        for (int r = 0; r < 4; ++r) {
            int t = tm * 16 + l4 * 4 + r;
            int i = (t * 147) >> 10;       // t/7 for t<64
            int j = t - i * 7;
            int yy = y + i - 3;
            int yc = yy < 0 ? 0 : (yy > 63 ? 63 : yy);
            row64[tm][r] = yc * 64;
            jm3[tm][r]   = j - 3;
            rokb |= ((unsigned)yy < 64u ? 1u : 0u) << (tm * 4 + r);
        }
    // t = 48 (i=6, j=6), contributes only on l4==0 lanes
    const int  yy48  = y + 3;
    const int  row48 = (yy48 > 63 ? 63 : yy48) * 64;
    const bool rok48 = (yy48 < 64) && (l4 == 0);

    #pragma unroll 1
    for (int iter = 0; iter < 4; ++iter) {
        const int g = gy * 16 + iter * 4 + wave;

        f32x4 acc[4][4];
        #pragma unroll
        for (int tm = 0; tm < 4; ++tm)
            #pragma unroll
            for (int pn = 0; pn < 4; ++pn) acc[tm][pn] = (f32x4)(0.f);

        const char* kwg = (const char*)kwb + (size_t)g * 8192;
        #pragma unroll
        for (int ks = 0; ks < 2; ++ks) {
            bf16x8 ka[4];
            #pragma unroll
            for (int tm = 0; tm < 4; ++tm) {
                int byte = (tm * 16 + l15) * 128 + ks * 64 + l4 * 16;
                ka[tm] = *(const bf16x8*)(kwg + byte);
            }
            #pragma unroll
            for (int tm = 0; tm < 4; ++tm)
                #pragma unroll
                for (int pn = 0; pn < 4; ++pn)
                    acc[tm][pn] = __builtin_amdgcn_mfma_f32_16x16x32_bf16(
                        ka[tm], hb[ks][pn], acc[tm][pn], 0, 0, 0);
        }

        // bias rows for this lane (r dim): kbp[g][tm*16 + l4*4 .. +3]
        #pragma unroll
        for (int tm = 0; tm < 4; ++tm) {
            f32x4 kv = *(const f32x4*)(kbp + g * 64 + tm * 16 + l4 * 4);
            #pragma unroll
            for (int pn = 0; pn < 4; ++pn)
                #pragma unroll
                for (int r = 0; r < 4; ++r) acc[tm][pn][r] += kv[r];
        }

        // norm: ssq over 49 taps; mean from u-rows (t=49 hi + t=50 lo + bsum)
        float m_all[4], inv_[4];
        #pragma unroll
        for (int pn = 0; pn < 4; ++pn) {
            float ssq = 0.f;
            #pragma unroll
            for (int tm = 0; tm < 3; ++tm)
                #pragma unroll
                for (int r = 0; r < 4; ++r) {
                    float e = acc[tm][pn][r];
                    ssq = fmaf(e, e, ssq);
                }
            float e48 = acc[3][pn][0];
            ssq += (l4 == 0) ? e48 * e48 : 0.f;
            ssq += __shfl_xor(ssq, 16);
            ssq += __shfl_xor(ssq, 32);
            // rows t=49 (r=1, has +bsum) and t=50 (r=2) live on l4==0 lanes
            float mr = acc[3][pn][1] + acc[3][pn][2];
            float m  = __shfl(mr, l15) * (1.f / 49.f);
            float ss = fmaxf(ssq - 49.f * m * m, 0.f);
            m_all[pn] = m;
            inv_[pn]  = 1.f / fmaxf(sqrtf(ss), 1e-6f);
        }

        // involution straight from global x (L2-hot): 13 taps x 4 pn
        const float* xg = x + ((size_t)(b * G_ + g)) * HW_;
        float kx[4] = {0.f, 0.f, 0.f, 0.f};
        float xs[4] = {0.f, 0.f, 0.f, 0.f};
        #pragma unroll
        for (int tm = 0; tm < 3; ++tm)
            #pragma unroll
            for (int r = 0; r < 4; ++r) {
                const bool rok  = (rokb >> (tm * 4 + r)) & 1u;
                const int  base = row64[tm][r];
                const int  cj   = jm3[tm][r];
                #pragma unroll
                for (int pn = 0; pn < 4; ++pn) {
                    int  col = l15 + pn * 16 + cj;
                    bool cv  = (pn == 0) ? (col >= 0)
                             : (pn == 3) ? (col < 64) : true;
                    int  colc = (pn == 0) ? (col < 0 ? 0 : col)
                              : (pn == 3) ? (col > 63 ? 63 : col) : col;
                    float xv = xg[base + colc];
                    xv = (rok && cv) ? xv : 0.f;
                    kx[pn] = fmaf(acc[tm][pn][r], xv, kx[pn]);
                    xs[pn] += xv;
                }
            }
        {   // t = 48
            #pragma unroll
            for (int pn = 0; pn < 4; ++pn) {
                int  col  = l15 + pn * 16 + 3;
                bool cv   = (pn == 3) ? (col < 64) : true;
                int  colc = (pn == 3) ? (col > 63 ? 63 : col) : col;
                float xv = xg[row48 + colc];
                xv = (rok48 && cv) ? xv : 0.f;
                kx[pn] = fmaf(acc[3][pn][0], xv, kx[pn]);
                xs[pn] += xv;
            }
        }
        float ov[4];
        #pragma unroll
        for (int pn = 0; pn < 4; ++pn) {
            float k2 = kx[pn];
            k2 += __shfl_xor(k2, 16);
            k2 += __shfl_xor(k2, 32);
            float x2 = xs[pn];
            x2 += __shfl_xor(x2, 16);
            x2 += __shfl_xor(x2, 32);
            ov[pn] = (k2 - m_all[pn] * x2) * inv_[pn];
        }
        float outv = (l4 == 0) ? ov[0] : (l4 == 1) ? ov[1] : (l4 == 2) ? ov[2] : ov[3];
        out[((size_t)(b * G_ + g)) * HW_ + y * W_ + lane] = outv;
    }
}

// --------------------------------------------- tier-2 hv (single-stage) ----
__global__ __launch_bounds__(256) void hv_kernel(
    const float* __restrict__ x, const float* __restrict__ rwT,
    const float* __restrict__ betp, ushort* __restrict__ hv)
{
    const int lane = threadIdx.x & 63;
    const int q    = __builtin_amdgcn_readfirstlane(threadIdx.x >> 6);
    const int p    = blockIdx.x * 64 + lane;
    const int b    = p >> 12;
    const int hw   = p & 4095;
    float acc[16];
    #pragma unroll
    for (int j = 0; j < 16; ++j) acc[j] = betp[q * 16 + j];
    const float* xp = x + (size_t)b * C_ * HW_ + hw;
    #pragma unroll 8
    for (int k = 0; k < C_; ++k) {
        float xk = xp[(size_t)k * HW_];
        const float* rw = rwT + k * HID_ + q * 16;
        #pragma unroll
        for (int j = 0; j < 16; ++j) acc[j] = fmaf(xk, rw[j], acc[j]);
    }
    union { ushort s[16]; uint4 v[2]; } u;
    #pragma unroll
    for (int j = 0; j < 16; ++j) u.s[j] = f2bf(fmaxf(acc[j], 0.f));
    uint4* dst = (uint4*)(hv + (size_t)p * HID_ + q * 16);
    dst[0] = u.v[0];
    dst[1] = u.v[1];
}

// ---------------------------------------------------- fallback (no ws) ----
__global__ __launch_bounds__(256) void invol_fallback(
    const float* __restrict__ x, const float* __restrict__ reduce_w,
    const float* __restrict__ bn_gamma, const float* __restrict__ bn_beta,
    const float* __restrict__ bn_mean, const float* __restrict__ bn_var,
    const float* __restrict__ kw, const float* __restrict__ kb,
    float* __restrict__ out)
{
    __shared__ float rwT[C_][HID_ + 4];
    __shared__ float bns[HID_];
    __shared__ float bnb[HID_];
    const int tid = threadIdx.x;
    const int b  = blockIdx.z;
    const int g0 = blockIdx.y * 32;
    const int p  = blockIdx.x * 256 + tid;
    const int py = p >> 6;
    const int px = p & 63;
    #pragma unroll 1
    for (int o = 0; o < HID_; ++o) rwT[tid][o] = reduce_w[o * C_ + tid];
    if (tid < HID_) {
        float inv = bn_gamma[tid] * rsqrtf(bn_var[tid] + BN_EPS);
        bns[tid] = inv;
        bnb[tid] = bn_beta[tid] - bn_mean[tid] * inv;
    }
    __syncthreads();
    float hvv[HID_];
    #pragma unroll
    for (int o = 0; o < HID_; ++o) hvv[o] = 0.f;
    const float* xb = x + (size_t)b * C_ * HW_ + p;
    #pragma unroll 4
    for (int k = 0; k < C_; ++k) {
        float xk = xb[(size_t)k * HW_];
        const float4* wr = (const float4*)&rwT[k][0];
        #pragma unroll
        for (int o4 = 0; o4 < HID_ / 4; ++o4) {
            float4 w = wr[o4];
            hvv[o4*4+0] = fmaf(xk, w.x, hvv[o4*4+0]);
            hvv[o4*4+1] = fmaf(xk, w.y, hvv[o4*4+1]);
            hvv[o4*4+2] = fmaf(xk, w.z, hvv[o4*4+2]);
            hvv[o4*4+3] = fmaf(xk, w.w, hvv[o4*4+3]);
        }
    }
    #pragma unroll
    for (int o = 0; o < HID_; ++o) hvv[o] = fmaxf(fmaf(hvv[o], bns[o], bnb[o]), 0.f);
    #pragma unroll 1
    for (int gi = 0; gi < 32; ++gi) {
        const int g = g0 + gi;
        const float* kwg = kw + (size_t)g * KK_ * HID_;
        float acc[KK_];
        #pragma unroll
        for (int t = 0; t < KK_; ++t) {
            float a = kb[g * KK_ + t];
            const float4* row = (const float4*)(kwg + t * HID_);
            #pragma unroll
            for (int k4 = 0; k4 < HID_ / 4; ++k4) {
                float4 w = row[k4];
                a = fmaf(w.x, hvv[k4*4+0], a);
                a = fmaf(w.y, hvv[k4*4+1], a);
                a = fmaf(w.z, hvv[k4*4+2], a);
                a = fmaf(w.w, hvv[k4*4+3], a);
            }
            acc[t] = a;
        }
        float mean = 0.f;
        #pragma unroll
        for (int t = 0; t < KK_; ++t) mean += acc[t];
        mean *= (1.f / 49.f);
        float ss = 0.f;
        #pragma unroll
        for (int t = 0; t < KK_; ++t) { acc[t] -= mean; ss = fmaf(acc[t], acc[t], ss); }
        float inv = 1.f / fmaxf(sqrtf(ss), 1e-6f);
        const float* xg = x + ((size_t)(b * G_ + g)) * HW_;
        float oacc = 0.f;
        #pragma unroll
        for (int i = 0; i < KS_; ++i) {
            int yv = py + i - 3;
            bool rok = ((unsigned)yv < (unsigned)H_);
            const float* xrow = xg + yv * W_;
            #pragma unroll
            for (int j = 0; j < KS_; ++j) {
                int xx = px + j - 3;
                bool ok = rok && ((unsigned)xx < (unsigned)W_);
                float v = ok ? xrow[xx] : 0.f;
                oacc = fmaf(v, acc[i*7+j], oacc);
            }
        }
        out[((size_t)(b * G_ + g)) * HW_ + p] = oacc * inv;
    }
}

extern "C" void kernel_launch(void* const* d_in, const int* in_sizes, int n_in,
                              void* d_out, int out_size, void* d_ws, size_t ws_size,
                              hipStream_t stream) {
    const float* x        = (const float*)d_in[0];
    const float* reduce_w = (const float*)d_in[1];
    const float* bn_gamma = (const float*)d_in[2];
    const float* bn_beta  = (const float*)d_in[3];
    const float* bn_mean  = (const float*)d_in[4];
    const float* bn_var   = (const float*)d_in[5];
    const float* kproj_w  = (const float*)d_in[6];
    const float* kproj_b  = (const float*)d_in[7];
    float* out = (float*)d_out;
    const int B   = in_sizes[0] / (C_ * HW_);
    const int npx = B * HW_;

    size_t kwb_off = 0;
    size_t kwb_sz  = (size_t)G_ * 64 * 64 * 2;        // 2 MB
    size_t kbp_off = kwb_off + kwb_sz;
    size_t kbp_sz  = (size_t)G_ * 64 * 4;             // 64 KB
    size_t rwt_off = kbp_off + kbp_sz;
    size_t rwt_sz  = (size_t)C_ * HID_ * 4;           // 64 KB
    size_t bet_off = rwt_off + rwt_sz;
    size_t bet_sz  = 256;
    size_t hv_off  = bet_off + bet_sz;
    size_t hv_sz   = (size_t)npx * HID_ * 2;          // 2 MB
    size_t hvp_off = hv_off + hv_sz;
    size_t hvp_sz  = (size_t)4 * HID_ * npx * 4;      // 16 MB
    size_t need2   = hvp_off;                          // without hvp
    size_t need    = hvp_off + hvp_sz;

    if (ws_size < need2) {
        dim3 grid(HW_ / 256, G_ / 32, B);
        invol_fallback<<<grid, 256, 0, stream>>>(x, reduce_w, bn_gamma, bn_beta,
                                                 bn_mean, bn_var, kproj_w, kproj_b, out);
        return;
    }

    ushort* kwb  = (ushort*)((char*)d_ws + kwb_off);
    float*  kbp  = (float*)((char*)d_ws + kbp_off);
    float*  rwT  = (float*)((char*)d_ws + rwt_off);
    float*  betp = (float*)((char*)d_ws + bet_off);
    ushort* hv   = (ushort*)((char*)d_ws + hv_off);
    float*  hvp  = (float*)((char*)d_ws + hvp_off);

    prep_kernel<<<dim3(258 + G_), 256, 0, stream>>>(kproj_w, kproj_b, reduce_w,
                                                    bn_gamma, bn_beta, bn_mean, bn_var,
                                                    kwb, rwT, betp, kbp);
    if (ws_size >= need) {
        hv1_kernel<<<dim3(npx / 64, 4), 256, 0, stream>>>(x, rwT, hvp, npx);
        hv2_kernel<<<dim3(npx / 256, 16), 256, 0, stream>>>(hvp, betp, hv, npx);
    } else {
        hv_kernel<<<dim3(npx / 64), 256, 0, stream>>>(x, rwT, betp, hv);
    }
    invol_main<<<dim3(B * H_, 16), 256, 0, stream>>>(x, hv, kwb, kbp, out);
}

// Round 8
// 151.315 us; speedup vs baseline: 1.6907x; 1.6907x over previous
//
#include <hip/hip_runtime.h>

// Involution via bf16 MFMA tap-GEMM, operand-swapped (D[t][px]).
// R8: block = (image, group, 32-row half). kw frags + bias hoisted to
// block scope (loaded ONCE, reused 8 rows/wave); channel x staged once in
// LDS with zero-padded columns ([38][72]) so the involution inner loop is
// pure ds_read + fma with no column masks; hv row frags are the only
// per-row global loads. 8-row loop gives the compiler pipelining room.

#define C_    256
#define HID_  64
#define KS_   7
#define KK_   49
#define G_    256
#define H_    64
#define W_    64
#define HW_   4096
#define BN_EPS 1e-5f

typedef __attribute__((ext_vector_type(8))) short bf16x8;
typedef __attribute__((ext_vector_type(4))) float f32x4;

__device__ __forceinline__ ushort f2bf(float f) {
    unsigned u = __float_as_uint(f);
    return (ushort)((u + 0x7fffu + ((u >> 16) & 1u)) >> 16);   // RNE
}
__device__ __forceinline__ float bf2f(ushort s) {
    return __uint_as_float((unsigned)s << 16);
}

// ---------------------------------------------------------------- prep ----
// blocks 0..255:  kwb[g][t][k] bf16 (t<49 data, 51..63 zero; skip t=49,50)
// block 256:      rwT[k][o] = reduce_w[o][k]*bn_inv[o]; betp[o]
// block 257:      kbp[g][t] = bias (t<49), 0 (t in 50..63); t=49 owned below
// blocks 258+g:   kwb[g][49/50][k] = colsum(kw) hi/lo; kbp[g][49] = sum(kb)
__global__ __launch_bounds__(256) void prep_kernel(
    const float* __restrict__ kw, const float* __restrict__ kb,
    const float* __restrict__ reduce_w,
    const float* __restrict__ bn_gamma, const float* __restrict__ bn_beta,
    const float* __restrict__ bn_mean, const float* __restrict__ bn_var,
    ushort* __restrict__ kwb, float* __restrict__ rwT, float* __restrict__ betp,
    float* __restrict__ kbp)
{
    const int bid = blockIdx.x;
    if (bid < 256) {
        int idx  = bid * 256 + threadIdx.x;
        int base = idx * 16;
        int g    = base >> 12;
        int rem  = base & 4095;
        int t    = rem >> 6;
        int k0   = rem & 63;
        if (t == 49 || t == 50) return;      // owned by u-row blocks
        union { ushort s[16]; uint4 v[2]; } u;
        if (t < KK_) {
            const float* src = kw + ((size_t)(g * KK_ + t)) * HID_ + k0;
            #pragma unroll
            for (int i = 0; i < 16; ++i) u.s[i] = f2bf(src[i]);
        } else {
            #pragma unroll
            for (int i = 0; i < 16; ++i) u.s[i] = 0;
        }
        uint4* dst = (uint4*)(kwb + base);
        dst[0] = u.v[0];
        dst[1] = u.v[1];
    } else if (bid == 256) {
        int k = threadIdx.x;
        #pragma unroll 1
        for (int o = 0; o < HID_; ++o) {
            float inv = bn_gamma[o] * rsqrtf(bn_var[o] + BN_EPS);
            rwT[k * HID_ + o] = reduce_w[o * C_ + k] * inv;
        }
        if (k < HID_) {
            float inv = bn_gamma[k] * rsqrtf(bn_var[k] + BN_EPS);
            betp[k] = bn_beta[k] - bn_mean[k] * inv;
        }
    } else if (bid == 257) {
        for (int i = threadIdx.x; i < G_ * 64; i += 256) {
            int g = i >> 6, t = i & 63;
            if (t == 49) continue;           // written by u-row block
            kbp[i] = (t < KK_) ? kb[g * KK_ + t] : 0.f;
        }
    } else {
        const int g = bid - 258;
        __shared__ float part[4][64];
        const int k  = threadIdx.x & 63;
        const int pr = threadIdx.x >> 6;
        const int t0 = pr * 13;
        const int t1 = (t0 + 13 < KK_) ? t0 + 13 : KK_;
        float s = 0.f;
        for (int t = t0; t < t1; ++t)
            s += kw[((size_t)(g * KK_ + t)) * HID_ + k];
        part[pr][k] = s;
        __syncthreads();
        if (threadIdx.x < 64) {
            float u = part[0][k] + part[1][k] + part[2][k] + part[3][k];
            ushort uh = f2bf(u);
            ushort ul = f2bf(u - bf2f(uh));
            kwb[(size_t)g * 4096 + 49 * 64 + k] = uh;
            kwb[(size_t)g * 4096 + 50 * 64 + k] = ul;
            // bias-sum: wave-parallel reduce over the 49 taps
            float bs = (k < KK_) ? kb[g * KK_ + k] : 0.f;
            #pragma unroll
            for (int off = 32; off >= 1; off >>= 1) bs += __shfl_xor(bs, off);
            if (k == 0) kbp[g * 64 + 49] = bs;
        }
    }
}

// ----------------------------------------------------------------- hv1 ----
__global__ __launch_bounds__(256) void hv1_kernel(
    const float* __restrict__ x, const float* __restrict__ rwT,
    float* __restrict__ hvp, int npx)
{
    const int lane = threadIdx.x & 63;
    const int wq   = __builtin_amdgcn_readfirstlane(threadIdx.x >> 6);
    const int kq   = blockIdx.y;
    const int p    = blockIdx.x * 64 + lane;
    const int b    = p >> 12;
    const int hw   = p & 4095;

    float acc[16];
    #pragma unroll
    for (int j = 0; j < 16; ++j) acc[j] = 0.f;

    const float* xp = x + ((size_t)b * C_ + kq * 64) * HW_ + hw;
    const float* rw = rwT + (kq * 64) * HID_ + wq * 16;
    #pragma unroll 8
    for (int kk = 0; kk < 64; ++kk) {
        float xk = xp[(size_t)kk * HW_];
        #pragma unroll
        for (int j = 0; j < 16; ++j) acc[j] = fmaf(xk, rw[kk * HID_ + j], acc[j]);
    }
    float* dst = hvp + ((size_t)(kq * 64 + wq * 16)) * npx + p;
    #pragma unroll
    for (int j = 0; j < 16; ++j) dst[(size_t)j * npx] = acc[j];
}

// ----------------------------------------------------------------- hv2 ----
__global__ __launch_bounds__(256) void hv2_kernel(
    const float* __restrict__ hvp, const float* __restrict__ betp,
    ushort* __restrict__ hv, int npx)
{
    const int p  = blockIdx.x * 256 + threadIdx.x;
    const int o0 = blockIdx.y * 4;
    ushort s[4];
    #pragma unroll
    for (int j = 0; j < 4; ++j) {
        float v = 0.f;
        #pragma unroll
        for (int kq = 0; kq < 4; ++kq)
            v += hvp[(size_t)(kq * 64 + o0 + j) * npx + p];
        s[j] = f2bf(fmaxf(v + betp[o0 + j], 0.f));
    }
    uint2 w;
    w.x = (uint)s[0] | ((uint)s[1] << 16);
    w.y = (uint)s[2] | ((uint)s[3] << 16);
    *(uint2*)(hv + (size_t)p * HID_ + o0) = w;
}

// ---------------------------------------------------------------- main ----
// Block = (b, g, half). x half staged once in LDS (zero-padded cols);
// kw frags + bias in registers for all 8 rows/wave.
__global__ __launch_bounds__(256) void invol_main(
    const float* __restrict__ x, const ushort* __restrict__ hv,
    const ushort* __restrict__ kwb, const float* __restrict__ kbp,
    float* __restrict__ out)
{
    __shared__ float x_s[38][72];          // 10944 B, rows y0-3..y0+34, cols -3..68

    const int tid  = threadIdx.x;
    const int lane = tid & 63;
    const int wave = __builtin_amdgcn_readfirstlane(tid >> 6);
    const int bg   = blockIdx.x;           // b*G + g
    const int b    = bg >> 8;
    const int g    = bg & 255;
    const int y0   = blockIdx.y << 5;      // 0 or 32
    const int l15  = lane & 15;
    const int l4   = lane >> 4;

    // ---- stage x half-tile (zero-padded columns) ----
    const float* xg = x + (size_t)bg * HW_;
    for (int idx = tid; idx < 38 * 72; idx += 256) {
        int r = idx / 72, c = idx - r * 72;
        int yy = y0 - 3 + r;
        int yc = yy < 0 ? 0 : (yy > 63 ? 63 : yy);
        int cc = c - 3;
        x_s[r][c] = ((unsigned)cc < 64u) ? xg[yc * 64 + cc] : 0.f;
    }

    // ---- kw A-frags + bias, once per block ----
    bf16x8 ka[2][4];
    const char* kwg = (const char*)kwb + (size_t)g * 8192;
    #pragma unroll
    for (int ks = 0; ks < 2; ++ks)
        #pragma unroll
        for (int tm = 0; tm < 4; ++tm) {
            int byte = (tm * 16 + l15) * 128 + ks * 64 + l4 * 16;
            ka[ks][tm] = *(const bf16x8*)(kwg + byte);
        }
    f32x4 kv[4];
    #pragma unroll
    for (int tm = 0; tm < 4; ++tm)
        kv[tm] = *(const f32x4*)(kbp + g * 64 + tm * 16 + l4 * 4);

    // ---- per-lane tap geometry: t = tm*16 + l4*4 + r (t<48) ----
    int po[3][4];     // i*72 + l15 + (j-3) + 3  (LDS word offset, row-relative)
    int im3[3][4];    // i - 3
    #pragma unroll
    for (int tm = 0; tm < 3; ++tm)
        #pragma unroll
        for (int r = 0; r < 4; ++r) {
            int t = tm * 16 + l4 * 4 + r;
            int i = (t * 147) >> 10;       // t/7 for t<64
            int j = t - i * 7;
            po[tm][r]  = i * 72 + l15 + j;   // (j-3)+3 = j
            im3[tm][r] = i - 3;
        }
    const int po48 = 6 * 72 + l15 + 6;

    __syncthreads();

    const int rowpix0 = (b << 12) + (y0 << 6);

    #pragma unroll 2
    for (int rr = 0; rr < 8; ++rr) {
        const int ry = rr * 4 + wave;      // 0..31
        const int y  = y0 + ry;

        // hv B-frags for this row (only per-row global loads)
        bf16x8 hb[2][4];
        #pragma unroll
        for (int ks = 0; ks < 2; ++ks)
            #pragma unroll
            for (int pn = 0; pn < 4; ++pn) {
                const char* p = (const char*)(hv +
                    (size_t)(rowpix0 + (ry << 6) + pn * 16 + l15) * HID_)
                    + ks * 64 + l4 * 16;
                hb[ks][pn] = *(const bf16x8*)p;
            }

        f32x4 acc[4][4];
        #pragma unroll
        for (int tm = 0; tm < 4; ++tm)
            #pragma unroll
            for (int pn = 0; pn < 4; ++pn) acc[tm][pn] = (f32x4)(0.f);
        #pragma unroll
        for (int ks = 0; ks < 2; ++ks)
            #pragma unroll
            for (int tm = 0; tm < 4; ++tm)
                #pragma unroll
                for (int pn = 0; pn < 4; ++pn)
                    acc[tm][pn] = __builtin_amdgcn_mfma_f32_16x16x32_bf16(
                        ka[ks][tm], hb[ks][pn], acc[tm][pn], 0, 0, 0);

        #pragma unroll
        for (int tm = 0; tm < 4; ++tm)
            #pragma unroll
            for (int pn = 0; pn < 4; ++pn)
                #pragma unroll
                for (int r = 0; r < 4; ++r) acc[tm][pn][r] += kv[tm][r];

        // norm: ssq over 49 taps; mean from u-rows (t=49 hi + t=50 lo + bsum)
        float m_all[4], inv_[4];
        #pragma unroll
        for (int pn = 0; pn < 4; ++pn) {
            float ssq = 0.f;
            #pragma unroll
            for (int tm = 0; tm < 3; ++tm)
                #pragma unroll
                for (int r = 0; r < 4; ++r) {
                    float e = acc[tm][pn][r];
                    ssq = fmaf(e, e, ssq);
                }
            float e48 = acc[3][pn][0];
            ssq += (l4 == 0) ? e48 * e48 : 0.f;
            ssq += __shfl_xor(ssq, 16);
            ssq += __shfl_xor(ssq, 32);
            float mr = acc[3][pn][1] + acc[3][pn][2];
            float m  = __shfl(mr, l15) * (1.f / 49.f);
            float ss = fmaxf(ssq - 49.f * m * m, 0.f);
            m_all[pn] = m;
            inv_[pn]  = 1.f / fmaxf(sqrtf(ss), 1e-6f);
        }

        // involution from LDS: addr = (ry+i)*72 + po; cols pre-zero-padded
        float kx[4] = {0.f, 0.f, 0.f, 0.f};
        float xs[4] = {0.f, 0.f, 0.f, 0.f};
        const float* xrow = &x_s[ry][0];
        #pragma unroll
        for (int tm = 0; tm < 3; ++tm)
            #pragma unroll
            for (int r = 0; r < 4; ++r) {
                const bool  rok  = (unsigned)(y + im3[tm][r]) < 64u;
                const float* bp  = xrow + po[tm][r];
                #pragma unroll
                for (int pn = 0; pn < 4; ++pn) {
                    float xv = bp[pn * 16];
                    xv = rok ? xv : 0.f;
                    kx[pn] = fmaf(acc[tm][pn][r], xv, kx[pn]);
                    xs[pn] += xv;
                }
            }
        {   // t = 48 (i=6,j=6): only l4==0 lanes carry the kernel value
            const bool  rok48 = ((y + 3) < 64) && (l4 == 0);
            const float* bp   = xrow + po48;
            #pragma unroll
            for (int pn = 0; pn < 4; ++pn) {
                float xv = bp[pn * 16];
                xv = rok48 ? xv : 0.f;
                kx[pn] = fmaf(acc[3][pn][0], xv, kx[pn]);
                xs[pn] += xv;
            }
        }
        float ov[4];
        #pragma unroll
        for (int pn = 0; pn < 4; ++pn) {
            float k2 = kx[pn];
            k2 += __shfl_xor(k2, 16);
            k2 += __shfl_xor(k2, 32);
            float x2 = xs[pn];
            x2 += __shfl_xor(x2, 16);
            x2 += __shfl_xor(x2, 32);
            ov[pn] = (k2 - m_all[pn] * x2) * inv_[pn];
        }
        float outv = (l4 == 0) ? ov[0] : (l4 == 1) ? ov[1] : (l4 == 2) ? ov[2] : ov[3];
        out[(size_t)bg * HW_ + (y << 6) + lane] = outv;
    }
}

// --------------------------------------------- tier-2 hv (single-stage) ----
__global__ __launch_bounds__(256) void hv_kernel(
    const float* __restrict__ x, const float* __restrict__ rwT,
    const float* __restrict__ betp, ushort* __restrict__ hv)
{
    const int lane = threadIdx.x & 63;
    const int q    = __builtin_amdgcn_readfirstlane(threadIdx.x >> 6);
    const int p    = blockIdx.x * 64 + lane;
    const int b    = p >> 12;
    const int hw   = p & 4095;
    float acc[16];
    #pragma unroll
    for (int j = 0; j < 16; ++j) acc[j] = betp[q * 16 + j];
    const float* xp = x + (size_t)b * C_ * HW_ + hw;
    #pragma unroll 8
    for (int k = 0; k < C_; ++k) {
        float xk = xp[(size_t)k * HW_];
        const float* rw = rwT + k * HID_ + q * 16;
        #pragma unroll
        for (int j = 0; j < 16; ++j) acc[j] = fmaf(xk, rw[j], acc[j]);
    }
    union { ushort s[16]; uint4 v[2]; } u;
    #pragma unroll
    for (int j = 0; j < 16; ++j) u.s[j] = f2bf(fmaxf(acc[j], 0.f));
    uint4* dst = (uint4*)(hv + (size_t)p * HID_ + q * 16);
    dst[0] = u.v[0];
    dst[1] = u.v[1];
}

// ---------------------------------------------------- fallback (no ws) ----
__global__ __launch_bounds__(256) void invol_fallback(
    const float* __restrict__ x, const float* __restrict__ reduce_w,
    const float* __restrict__ bn_gamma, const float* __restrict__ bn_beta,
    const float* __restrict__ bn_mean, const float* __restrict__ bn_var,
    const float* __restrict__ kw, const float* __restrict__ kb,
    float* __restrict__ out)
{
    __shared__ float rwT[C_][HID_ + 4];
    __shared__ float bns[HID_];
    __shared__ float bnb[HID_];
    const int tid = threadIdx.x;
    const int b  = blockIdx.z;
    const int g0 = blockIdx.y * 32;
    const int p  = blockIdx.x * 256 + tid;
    const int py = p >> 6;
    const int px = p & 63;
    #pragma unroll 1
    for (int o = 0; o < HID_; ++o) rwT[tid][o] = reduce_w[o * C_ + tid];
    if (tid < HID_) {
        float inv = bn_gamma[tid] * rsqrtf(bn_var[tid] + BN_EPS);
        bns[tid] = inv;
        bnb[tid] = bn_beta[tid] - bn_mean[tid] * inv;
    }
    __syncthreads();
    float hvv[HID_];
    #pragma unroll
    for (int o = 0; o < HID_; ++o) hvv[o] = 0.f;
    const float* xb = x + (size_t)b * C_ * HW_ + p;
    #pragma unroll 4
    for (int k = 0; k < C_; ++k) {
        float xk = xb[(size_t)k * HW_];
        const float4* wr = (const float4*)&rwT[k][0];
        #pragma unroll
        for (int o4 = 0; o4 < HID_ / 4; ++o4) {
            float4 w = wr[o4];
            hvv[o4*4+0] = fmaf(xk, w.x, hvv[o4*4+0]);
            hvv[o4*4+1] = fmaf(xk, w.y, hvv[o4*4+1]);
            hvv[o4*4+2] = fmaf(xk, w.z, hvv[o4*4+2]);
            hvv[o4*4+3] = fmaf(xk, w.w, hvv[o4*4+3]);
        }
    }
    #pragma unroll
    for (int o = 0; o < HID_; ++o) hvv[o] = fmaxf(fmaf(hvv[o], bns[o], bnb[o]), 0.f);
    #pragma unroll 1
    for (int gi = 0; gi < 32; ++gi) {
        const int g = g0 + gi;
        const float* kwg = kw + (size_t)g * KK_ * HID_;
        float acc[KK_];
        #pragma unroll
        for (int t = 0; t < KK_; ++t) {
            float a = kb[g * KK_ + t];
            const float4* row = (const float4*)(kwg + t * HID_);
            #pragma unroll
            for (int k4 = 0; k4 < HID_ / 4; ++k4) {
                float4 w = row[k4];
                a = fmaf(w.x, hvv[k4*4+0], a);
                a = fmaf(w.y, hvv[k4*4+1], a);
                a = fmaf(w.z, hvv[k4*4+2], a);
                a = fmaf(w.w, hvv[k4*4+3], a);
            }
            acc[t] = a;
        }
        float mean = 0.f;
        #pragma unroll
        for (int t = 0; t < KK_; ++t) mean += acc[t];
        mean *= (1.f / 49.f);
        float ss = 0.f;
        #pragma unroll
        for (int t = 0; t < KK_; ++t) { acc[t] -= mean; ss = fmaf(acc[t], acc[t], ss); }
        float inv = 1.f / fmaxf(sqrtf(ss), 1e-6f);
        const float* xg = x + ((size_t)(b * G_ + g)) * HW_;
        float oacc = 0.f;
        #pragma unroll
        for (int i = 0; i < KS_; ++i) {
            int yv = py + i - 3;
            bool rok = ((unsigned)yv < (unsigned)H_);
            const float* xrow = xg + yv * W_;
            #pragma unroll
            for (int j = 0; j < KS_; ++j) {
                int xx = px + j - 3;
                bool ok = rok && ((unsigned)xx < (unsigned)W_);
                float v = ok ? xrow[xx] : 0.f;
                oacc = fmaf(v, acc[i*7+j], oacc);
            }
        }
        out[((size_t)(b * G_ + g)) * HW_ + p] = oacc * inv;
    }
}

extern "C" void kernel_launch(void* const* d_in, const int* in_sizes, int n_in,
                              void* d_out, int out_size, void* d_ws, size_t ws_size,
                              hipStream_t stream) {
    const float* x        = (const float*)d_in[0];
    const float* reduce_w = (const float*)d_in[1];
    const float* bn_gamma = (const float*)d_in[2];
    const float* bn_beta  = (const float*)d_in[3];
    const float* bn_mean  = (const float*)d_in[4];
    const float* bn_var   = (const float*)d_in[5];
    const float* kproj_w  = (const float*)d_in[6];
    const float* kproj_b  = (const float*)d_in[7];
    float* out = (float*)d_out;
    const int B   = in_sizes[0] / (C_ * HW_);
    const int npx = B * HW_;

    size_t kwb_off = 0;
    size_t kwb_sz  = (size_t)G_ * 64 * 64 * 2;        // 2 MB
    size_t kbp_off = kwb_off + kwb_sz;
    size_t kbp_sz  = (size_t)G_ * 64 * 4;             // 64 KB
    size_t rwt_off = kbp_off + kbp_sz;
    size_t rwt_sz  = (size_t)C_ * HID_ * 4;           // 64 KB
    size_t bet_off = rwt_off + rwt_sz;
    size_t bet_sz  = 256;
    size_t hv_off  = bet_off + bet_sz;
    size_t hv_sz   = (size_t)npx * HID_ * 2;          // 2 MB
    size_t hvp_off = hv_off + hv_sz;
    size_t hvp_sz  = (size_t)4 * HID_ * npx * 4;      // 16 MB
    size_t need2   = hvp_off;                          // without hvp
    size_t need    = hvp_off + hvp_sz;

    if (ws_size < need2) {
        dim3 grid(HW_ / 256, G_ / 32, B);
        invol_fallback<<<grid, 256, 0, stream>>>(x, reduce_w, bn_gamma, bn_beta,
                                                 bn_mean, bn_var, kproj_w, kproj_b, out);
        return;
    }

    ushort* kwb  = (ushort*)((char*)d_ws + kwb_off);
    float*  kbp  = (float*)((char*)d_ws + kbp_off);
    float*  rwT  = (float*)((char*)d_ws + rwt_off);
    float*  betp = (float*)((char*)d_ws + bet_off);
    ushort* hv   = (ushort*)((char*)d_ws + hv_off);
    float*  hvp  = (float*)((char*)d_ws + hvp_off);

    prep_kernel<<<dim3(258 + G_), 256, 0, stream>>>(kproj_w, kproj_b, reduce_w,
                                                    bn_gamma, bn_beta, bn_mean, bn_var,
                                                    kwb, rwT, betp, kbp);
    if (ws_size >= need) {
        hv1_kernel<<<dim3(npx / 64, 4), 256, 0, stream>>>(x, rwT, hvp, npx);
        hv2_kernel<<<dim3(npx / 256, 16), 256, 0, stream>>>(hvp, betp, hv, npx);
    } else {
        hv_kernel<<<dim3(npx / 64), 256, 0, stream>>>(x, rwT, betp, hv);
    }
    invol_main<<<dim3(B * G_, 2), 256, 0, stream>>>(x, hv, kwb, kbp, out);
}

// Round 9
// 148.756 us; speedup vs baseline: 1.7198x; 1.0172x over previous
//
#include <hip/hip_runtime.h>

// Involution via bf16 MFMA tap-GEMM, operand-swapped (D[t][px]).
// R9: cut per-row issue work (kernel is issue-bound, model ~1250cy/row):
//  - bias as MFMA accumulator INIT (not post-add): -64 VALU/row, and
//    zero-tap rows become exactly 0 -> drop l4 masks on t48/ssq paths
//  - x_s rows zero-padded (not clamped): drop 52 rok cndmasks/row
//  - xs (window sum of x) via one-time separable 7x7 box filter in LDS
//    (hs h-pass + vs v-pass, sliding window): per-row 52 adds + 8 shfl
//    replaced by ONE ds_read of vs_s[ry][lane].

#define C_    256
#define HID_  64
#define KS_   7
#define KK_   49
#define G_    256
#define H_    64
#define W_    64
#define HW_   4096
#define BN_EPS 1e-5f

typedef __attribute__((ext_vector_type(8))) short bf16x8;
typedef __attribute__((ext_vector_type(4))) float f32x4;

__device__ __forceinline__ ushort f2bf(float f) {
    unsigned u = __float_as_uint(f);
    return (ushort)((u + 0x7fffu + ((u >> 16) & 1u)) >> 16);   // RNE
}
__device__ __forceinline__ float bf2f(ushort s) {
    return __uint_as_float((unsigned)s << 16);
}

// ---------------------------------------------------------------- prep ----
// blocks 0..255:  kwb[g][t][k] bf16 (t<49 data, 51..63 zero; skip t=49,50)
// block 256:      rwT[k][o] = reduce_w[o][k]*bn_inv[o]; betp[o]
// block 257:      kbp[g][t] = bias (t<49), 0 (t in 50..63); t=49 owned below
// blocks 258+g:   kwb[g][49/50][k] = colsum(kw) hi/lo; kbp[g][49] = sum(kb)
__global__ __launch_bounds__(256) void prep_kernel(
    const float* __restrict__ kw, const float* __restrict__ kb,
    const float* __restrict__ reduce_w,
    const float* __restrict__ bn_gamma, const float* __restrict__ bn_beta,
    const float* __restrict__ bn_mean, const float* __restrict__ bn_var,
    ushort* __restrict__ kwb, float* __restrict__ rwT, float* __restrict__ betp,
    float* __restrict__ kbp)
{
    const int bid = blockIdx.x;
    if (bid < 256) {
        int idx  = bid * 256 + threadIdx.x;
        int base = idx * 16;
        int g    = base >> 12;
        int rem  = base & 4095;
        int t    = rem >> 6;
        int k0   = rem & 63;
        if (t == 49 || t == 50) return;      // owned by u-row blocks
        union { ushort s[16]; uint4 v[2]; } u;
        if (t < KK_) {
            const float* src = kw + ((size_t)(g * KK_ + t)) * HID_ + k0;
            #pragma unroll
            for (int i = 0; i < 16; ++i) u.s[i] = f2bf(src[i]);
        } else {
            #pragma unroll
            for (int i = 0; i < 16; ++i) u.s[i] = 0;
        }
        uint4* dst = (uint4*)(kwb + base);
        dst[0] = u.v[0];
        dst[1] = u.v[1];
    } else if (bid == 256) {
        int k = threadIdx.x;
        #pragma unroll 1
        for (int o = 0; o < HID_; ++o) {
            float inv = bn_gamma[o] * rsqrtf(bn_var[o] + BN_EPS);
            rwT[k * HID_ + o] = reduce_w[o * C_ + k] * inv;
        }
        if (k < HID_) {
            float inv = bn_gamma[k] * rsqrtf(bn_var[k] + BN_EPS);
            betp[k] = bn_beta[k] - bn_mean[k] * inv;
        }
    } else if (bid == 257) {
        for (int i = threadIdx.x; i < G_ * 64; i += 256) {
            int g = i >> 6, t = i & 63;
            if (t == 49) continue;           // written by u-row block
            kbp[i] = (t < KK_) ? kb[g * KK_ + t] : 0.f;
        }
    } else {
        const int g = bid - 258;
        __shared__ float part[4][64];
        const int k  = threadIdx.x & 63;
        const int pr = threadIdx.x >> 6;
        const int t0 = pr * 13;
        const int t1 = (t0 + 13 < KK_) ? t0 + 13 : KK_;
        float s = 0.f;
        for (int t = t0; t < t1; ++t)
            s += kw[((size_t)(g * KK_ + t)) * HID_ + k];
        part[pr][k] = s;
        __syncthreads();
        if (threadIdx.x < 64) {
            float u = part[0][k] + part[1][k] + part[2][k] + part[3][k];
            ushort uh = f2bf(u);
            ushort ul = f2bf(u - bf2f(uh));
            kwb[(size_t)g * 4096 + 49 * 64 + k] = uh;
            kwb[(size_t)g * 4096 + 50 * 64 + k] = ul;
            // bias-sum: wave-parallel reduce over the 49 taps
            float bs = (k < KK_) ? kb[g * KK_ + k] : 0.f;
            #pragma unroll
            for (int off = 32; off >= 1; off >>= 1) bs += __shfl_xor(bs, off);
            if (k == 0) kbp[g * 64 + 49] = bs;
        }
    }
}

// ----------------------------------------------------------------- hv1 ----
__global__ __launch_bounds__(256) void hv1_kernel(
    const float* __restrict__ x, const float* __restrict__ rwT,
    float* __restrict__ hvp, int npx)
{
    const int lane = threadIdx.x & 63;
    const int wq   = __builtin_amdgcn_readfirstlane(threadIdx.x >> 6);
    const int kq   = blockIdx.y;
    const int p    = blockIdx.x * 64 + lane;
    const int b    = p >> 12;
    const int hw   = p & 4095;

    float acc[16];
    #pragma unroll
    for (int j = 0; j < 16; ++j) acc[j] = 0.f;

    const float* xp = x + ((size_t)b * C_ + kq * 64) * HW_ + hw;
    const float* rw = rwT + (kq * 64) * HID_ + wq * 16;
    #pragma unroll 8
    for (int kk = 0; kk < 64; ++kk) {
        float xk = xp[(size_t)kk * HW_];
        #pragma unroll
        for (int j = 0; j < 16; ++j) acc[j] = fmaf(xk, rw[kk * HID_ + j], acc[j]);
    }
    float* dst = hvp + ((size_t)(kq * 64 + wq * 16)) * npx + p;
    #pragma unroll
    for (int j = 0; j < 16; ++j) dst[(size_t)j * npx] = acc[j];
}

// ----------------------------------------------------------------- hv2 ----
__global__ __launch_bounds__(256) void hv2_kernel(
    const float* __restrict__ hvp, const float* __restrict__ betp,
    ushort* __restrict__ hv, int npx)
{
    const int p  = blockIdx.x * 256 + threadIdx.x;
    const int o0 = blockIdx.y * 4;
    ushort s[4];
    #pragma unroll
    for (int j = 0; j < 4; ++j) {
        float v = 0.f;
        #pragma unroll
        for (int kq = 0; kq < 4; ++kq)
            v += hvp[(size_t)(kq * 64 + o0 + j) * npx + p];
        s[j] = f2bf(fmaxf(v + betp[o0 + j], 0.f));
    }
    uint2 w;
    w.x = (uint)s[0] | ((uint)s[1] << 16);
    w.y = (uint)s[2] | ((uint)s[3] << 16);
    *(uint2*)(hv + (size_t)p * HID_ + o0) = w;
}

// ---------------------------------------------------------------- main ----
// Block = (b, g, half). x half staged once (zero-padded rows+cols);
// 7x7 window sums precomputed (separable box filter); kw frags + bias
// in registers for all 8 rows/wave; bias folded into acc init.
__global__ __launch_bounds__(256) void invol_main(
    const float* __restrict__ x, const ushort* __restrict__ hv,
    const ushort* __restrict__ kwb, const float* __restrict__ kbp,
    float* __restrict__ out)
{
    __shared__ float x_s[38][72];          // 10944 B, zero-padded window
    __shared__ float hs_s[38][64];         //  9728 B, horizontal 7-sums
    __shared__ float vs_s[32][64];         //  8192 B, full 7x7 window sums

    const int tid  = threadIdx.x;
    const int lane = tid & 63;
    const int wave = __builtin_amdgcn_readfirstlane(tid >> 6);
    const int bg   = blockIdx.x;           // b*G + g
    const int b    = bg >> 8;
    const int g    = bg & 255;
    const int y0   = blockIdx.y << 5;      // 0 or 32
    const int l15  = lane & 15;
    const int l4   = lane >> 4;

    // ---- stage x half-tile (zero-padded rows AND columns) ----
    const float* xg = x + (size_t)bg * HW_;
    for (int idx = tid; idx < 38 * 72; idx += 256) {
        int r = idx / 72, c = idx - r * 72;
        int yy = y0 - 3 + r;
        int cc = c - 3;
        bool v = ((unsigned)yy < 64u) && ((unsigned)cc < 64u);
        x_s[r][c] = v ? xg[yy * 64 + cc] : 0.f;
    }

    // ---- kw A-frags + bias, once per block ----
    bf16x8 ka[2][4];
    const char* kwg = (const char*)kwb + (size_t)g * 8192;
    #pragma unroll
    for (int ks = 0; ks < 2; ++ks)
        #pragma unroll
        for (int tm = 0; tm < 4; ++tm) {
            int byte = (tm * 16 + l15) * 128 + ks * 64 + l4 * 16;
            ka[ks][tm] = *(const bf16x8*)(kwg + byte);
        }
    f32x4 kv[4];
    #pragma unroll
    for (int tm = 0; tm < 4; ++tm)
        kv[tm] = *(const f32x4*)(kbp + g * 64 + tm * 16 + l4 * 4);

    // ---- per-lane tap geometry: t = tm*16 + l4*4 + r (t<48) ----
    int po[3][4];     // i*72 + l15 + j  (LDS word offset, row-relative)
    #pragma unroll
    for (int tm = 0; tm < 3; ++tm)
        #pragma unroll
        for (int r = 0; r < 4; ++r) {
            int t = tm * 16 + l4 * 4 + r;
            int i = (t * 147) >> 10;       // t/7 for t<64
            int j = t - i * 7;
            po[tm][r] = i * 72 + l15 + j;
        }
    const int po48 = 6 * 72 + l15 + 6;

    __syncthreads();

    // ---- h-pass: hs_s[r][c] = sum_{j=0..6} x_s[r][c+j], sliding ----
    if (tid < 152) {
        int r  = tid >> 2;
        int c0 = (tid & 3) << 4;
        float s = 0.f;
        #pragma unroll
        for (int j = 0; j < 7; ++j) s += x_s[r][c0 + j];
        hs_s[r][c0] = s;
        #pragma unroll
        for (int c = 1; c < 16; ++c) {
            s += x_s[r][c0 + c + 6] - x_s[r][c0 + c - 1];
            hs_s[r][c0 + c] = s;
        }
    }
    __syncthreads();
    // ---- v-pass: vs_s[ry][c] = sum_{i=0..6} hs_s[ry+i][c], sliding ----
    {
        int c   = tid & 63;
        int ry0 = (tid >> 6) << 3;
        float s = 0.f;
        #pragma unroll
        for (int i = 0; i < 7; ++i) s += hs_s[ry0 + i][c];
        vs_s[ry0][c] = s;
        #pragma unroll
        for (int k = 1; k < 8; ++k) {
            s += hs_s[ry0 + k + 6][c] - hs_s[ry0 + k - 1][c];
            vs_s[ry0 + k][c] = s;
        }
    }
    __syncthreads();

    const int rowpix0 = (b << 12) + (y0 << 6);

    #pragma unroll 2
    for (int rr = 0; rr < 8; ++rr) {
        const int ry = rr * 4 + wave;      // 0..31
        const int y  = y0 + ry;

        // hv B-frags for this row (only per-row global loads)
        bf16x8 hb[2][4];
        #pragma unroll
        for (int ks = 0; ks < 2; ++ks)
            #pragma unroll
            for (int pn = 0; pn < 4; ++pn) {
                const char* p = (const char*)(hv +
                    (size_t)(rowpix0 + (ry << 6) + pn * 16 + l15) * HID_)
                    + ks * 64 + l4 * 16;
                hb[ks][pn] = *(const bf16x8*)p;
            }

        // acc init = bias (zero-padded taps get exactly 0)
        f32x4 acc[4][4];
        #pragma unroll
        for (int tm = 0; tm < 4; ++tm)
            #pragma unroll
            for (int pn = 0; pn < 4; ++pn) acc[tm][pn] = kv[tm];
        #pragma unroll
        for (int ks = 0; ks < 2; ++ks)
            #pragma unroll
            for (int tm = 0; tm < 4; ++tm)
                #pragma unroll
                for (int pn = 0; pn < 4; ++pn)
                    acc[tm][pn] = __builtin_amdgcn_mfma_f32_16x16x32_bf16(
                        ka[ks][tm], hb[ks][pn], acc[tm][pn], 0, 0, 0);

        // norm: ssq over 49 taps; mean from u-rows (t=49 hi + t=50 lo + bsum)
        float m_all[4], inv_[4];
        #pragma unroll
        for (int pn = 0; pn < 4; ++pn) {
            float ssq = 0.f;
            #pragma unroll
            for (int tm = 0; tm < 3; ++tm)
                #pragma unroll
                for (int r = 0; r < 4; ++r) {
                    float e = acc[tm][pn][r];
                    ssq = fmaf(e, e, ssq);
                }
            float e48 = acc[3][pn][0];     // 0 on l4!=0 lanes (zero tap rows)
            ssq = fmaf(e48, e48, ssq);
            ssq += __shfl_xor(ssq, 16);
            ssq += __shfl_xor(ssq, 32);
            float mr = acc[3][pn][1] + acc[3][pn][2];
            float m  = __shfl(mr, l15) * (1.f / 49.f);
            float ss = fmaxf(ssq - 49.f * m * m, 0.f);
            m_all[pn] = m;
            inv_[pn]  = 1.f / fmaxf(sqrtf(ss), 1e-6f);
        }

        // involution from LDS: rows pre-zeroed -> no masks anywhere
        float kx[4] = {0.f, 0.f, 0.f, 0.f};
        const float* xrow = &x_s[ry][0];
        #pragma unroll
        for (int tm = 0; tm < 3; ++tm)
            #pragma unroll
            for (int r = 0; r < 4; ++r) {
                const float* bp = xrow + po[tm][r];
                #pragma unroll
                for (int pn = 0; pn < 4; ++pn)
                    kx[pn] = fmaf(acc[tm][pn][r], bp[pn * 16], kx[pn]);
            }
        {   // t = 48: acc[3][pn][0] is 0 on l4!=0 lanes, no mask needed
            const float* bp = xrow + po48;
            #pragma unroll
            for (int pn = 0; pn < 4; ++pn)
                kx[pn] = fmaf(acc[3][pn][0], bp[pn * 16], kx[pn]);
        }
        // reduce kx across l4 groups, then select this lane's pixel
        float k2[4];
        #pragma unroll
        for (int pn = 0; pn < 4; ++pn) {
            float v = kx[pn];
            v += __shfl_xor(v, 16);
            v += __shfl_xor(v, 32);
            k2[pn] = v;
        }
        float k2s = (l4 == 0) ? k2[0] : (l4 == 1) ? k2[1] : (l4 == 2) ? k2[2] : k2[3];
        float ms  = (l4 == 0) ? m_all[0] : (l4 == 1) ? m_all[1] : (l4 == 2) ? m_all[2] : m_all[3];
        float is  = (l4 == 0) ? inv_[0] : (l4 == 1) ? inv_[1] : (l4 == 2) ? inv_[2] : inv_[3];
        float x2  = vs_s[ry][lane];        // window x-sum for this pixel
        out[(size_t)bg * HW_ + (y << 6) + lane] = (k2s - ms * x2) * is;
    }
}

// --------------------------------------------- tier-2 hv (single-stage) ----
__global__ __launch_bounds__(256) void hv_kernel(
    const float* __restrict__ x, const float* __restrict__ rwT,
    const float* __restrict__ betp, ushort* __restrict__ hv)
{
    const int lane = threadIdx.x & 63;
    const int q    = __builtin_amdgcn_readfirstlane(threadIdx.x >> 6);
    const int p    = blockIdx.x * 64 + lane;
    const int b    = p >> 12;
    const int hw   = p & 4095;
    float acc[16];
    #pragma unroll
    for (int j = 0; j < 16; ++j) acc[j] = betp[q * 16 + j];
    const float* xp = x + (size_t)b * C_ * HW_ + hw;
    #pragma unroll 8
    for (int k = 0; k < C_; ++k) {
        float xk = xp[(size_t)k * HW_];
        const float* rw = rwT + k * HID_ + q * 16;
        #pragma unroll
        for (int j = 0; j < 16; ++j) acc[j] = fmaf(xk, rw[j], acc[j]);
    }
    union { ushort s[16]; uint4 v[2]; } u;
    #pragma unroll
    for (int j = 0; j < 16; ++j) u.s[j] = f2bf(fmaxf(acc[j], 0.f));
    uint4* dst = (uint4*)(hv + (size_t)p * HID_ + q * 16);
    dst[0] = u.v[0];
    dst[1] = u.v[1];
}

// ---------------------------------------------------- fallback (no ws) ----
__global__ __launch_bounds__(256) void invol_fallback(
    const float* __restrict__ x, const float* __restrict__ reduce_w,
    const float* __restrict__ bn_gamma, const float* __restrict__ bn_beta,
    const float* __restrict__ bn_mean, const float* __restrict__ bn_var,
    const float* __restrict__ kw, const float* __restrict__ kb,
    float* __restrict__ out)
{
    __shared__ float rwT[C_][HID_ + 4];
    __shared__ float bns[HID_];
    __shared__ float bnb[HID_];
    const int tid = threadIdx.x;
    const int b  = blockIdx.z;
    const int g0 = blockIdx.y * 32;
    const int p  = blockIdx.x * 256 + tid;
    const int py = p >> 6;
    const int px = p & 63;
    #pragma unroll 1
    for (int o = 0; o < HID_; ++o) rwT[tid][o] = reduce_w[o * C_ + tid];
    if (tid < HID_) {
        float inv = bn_gamma[tid] * rsqrtf(bn_var[tid] + BN_EPS);
        bns[tid] = inv;
        bnb[tid] = bn_beta[tid] - bn_mean[tid] * inv;
    }
    __syncthreads();
    float hvv[HID_];
    #pragma unroll
    for (int o = 0; o < HID_; ++o) hvv[o] = 0.f;
    const float* xb = x + (size_t)b * C_ * HW_ + p;
    #pragma unroll 4
    for (int k = 0; k < C_; ++k) {
        float xk = xb[(size_t)k * HW_];
        const float4* wr = (const float4*)&rwT[k][0];
        #pragma unroll
        for (int o4 = 0; o4 < HID_ / 4; ++o4) {
            float4 w = wr[o4];
            hvv[o4*4+0] = fmaf(xk, w.x, hvv[o4*4+0]);
            hvv[o4*4+1] = fmaf(xk, w.y, hvv[o4*4+1]);
            hvv[o4*4+2] = fmaf(xk, w.z, hvv[o4*4+2]);
            hvv[o4*4+3] = fmaf(xk, w.w, hvv[o4*4+3]);
        }
    }
    #pragma unroll
    for (int o = 0; o < HID_; ++o) hvv[o] = fmaxf(fmaf(hvv[o], bns[o], bnb[o]), 0.f);
    #pragma unroll 1
    for (int gi = 0; gi < 32; ++gi) {
        const int g = g0 + gi;
        const float* kwg = kw + (size_t)g * KK_ * HID_;
        float acc[KK_];
        #pragma unroll
        for (int t = 0; t < KK_; ++t) {
            float a = kb[g * KK_ + t];
            const float4* row = (const float4*)(kwg + t * HID_);
            #pragma unroll
            for (int k4 = 0; k4 < HID_ / 4; ++k4) {
                float4 w = row[k4];
                a = fmaf(w.x, hvv[k4*4+0], a);
                a = fmaf(w.y, hvv[k4*4+1], a);
                a = fmaf(w.z, hvv[k4*4+2], a);
                a = fmaf(w.w, hvv[k4*4+3], a);
            }
            acc[t] = a;
        }
        float mean = 0.f;
        #pragma unroll
        for (int t = 0; t < KK_; ++t) mean += acc[t];
        mean *= (1.f / 49.f);
        float ss = 0.f;
        #pragma unroll
        for (int t = 0; t < KK_; ++t) { acc[t] -= mean; ss = fmaf(acc[t], acc[t], ss); }
        float inv = 1.f / fmaxf(sqrtf(ss), 1e-6f);
        const float* xg = x + ((size_t)(b * G_ + g)) * HW_;
        float oacc = 0.f;
        #pragma unroll
        for (int i = 0; i < KS_; ++i) {
            int yv = py + i - 3;
            bool rok = ((unsigned)yv < (unsigned)H_);
            const float* xrow = xg + yv * W_;
            #pragma unroll
            for (int j = 0; j < KS_; ++j) {
                int xx = px + j - 3;
                bool ok = rok && ((unsigned)xx < (unsigned)W_);
                float v = ok ? xrow[xx] : 0.f;
                oacc = fmaf(v, acc[i*7+j], oacc);
            }
        }
        out[((size_t)(b * G_ + g)) * HW_ + p] = oacc * inv;
    }
}

extern "C" void kernel_launch(void* const* d_in, const int* in_sizes, int n_in,
                              void* d_out, int out_size, void* d_ws, size_t ws_size,
                              hipStream_t stream) {
    const float* x        = (const float*)d_in[0];
    const float* reduce_w = (const float*)d_in[1];
    const float* bn_gamma = (const float*)d_in[2];
    const float* bn_beta  = (const float*)d_in[3];
    const float* bn_mean  = (const float*)d_in[4];
    const float* bn_var   = (const float*)d_in[5];
    const float* kproj_w  = (const float*)d_in[6];
    const float* kproj_b  = (const float*)d_in[7];
    float* out = (float*)d_out;
    const int B   = in_sizes[0] / (C_ * HW_);
    const int npx = B * HW_;

    size_t kwb_off = 0;
    size_t kwb_sz  = (size_t)G_ * 64 * 64 * 2;        // 2 MB
    size_t kbp_off = kwb_off + kwb_sz;
    size_t kbp_sz  = (size_t)G_ * 64 * 4;             // 64 KB
    size_t rwt_off = kbp_off + kbp_sz;
    size_t rwt_sz  = (size_t)C_ * HID_ * 4;           // 64 KB
    size_t bet_off = rwt_off + rwt_sz;
    size_t bet_sz  = 256;
    size_t hv_off  = bet_off + bet_sz;
    size_t hv_sz   = (size_t)npx * HID_ * 2;          // 2 MB
    size_t hvp_off = hv_off + hv_sz;
    size_t hvp_sz  = (size_t)4 * HID_ * npx * 4;      // 16 MB
    size_t need2   = hvp_off;                          // without hvp
    size_t need    = hvp_off + hvp_sz;

    if (ws_size < need2) {
        dim3 grid(HW_ / 256, G_ / 32, B);
        invol_fallback<<<grid, 256, 0, stream>>>(x, reduce_w, bn_gamma, bn_beta,
                                                 bn_mean, bn_var, kproj_w, kproj_b, out);
        return;
    }

    ushort* kwb  = (ushort*)((char*)d_ws + kwb_off);
    float*  kbp  = (float*)((char*)d_ws + kbp_off);
    float*  rwT  = (float*)((char*)d_ws + rwt_off);
    float*  betp = (float*)((char*)d_ws + bet_off);
    ushort* hv   = (ushort*)((char*)d_ws + hv_off);
    float*  hvp  = (float*)((char*)d_ws + hvp_off);

    prep_kernel<<<dim3(258 + G_), 256, 0, stream>>>(kproj_w, kproj_b, reduce_w,
                                                    bn_gamma, bn_beta, bn_mean, bn_var,
                                                    kwb, rwT, betp, kbp);
    if (ws_size >= need) {
        hv1_kernel<<<dim3(npx / 64, 4), 256, 0, stream>>>(x, rwT, hvp, npx);
        hv2_kernel<<<dim3(npx / 256, 16), 256, 0, stream>>>(hvp, betp, hv, npx);
    } else {
        hv_kernel<<<dim3(npx / 64), 256, 0, stream>>>(x, rwT, betp, hv);
    }
    invol_main<<<dim3(B * G_, 2), 256, 0, stream>>>(x, hv, kwb, kbp, out);
}